// Round 1
// baseline (1562.406 us; speedup 1.0000x reference)
//
#include <hip/hip_runtime.h>
#include <hip/hip_bf16.h>

// Decoder block, fp32 baseline.
// B=32, T=512, D=512, H=8, dh=64, FF=2048. N = B*T = 16384 rows.
//
// Pipeline:
//  0. pack Wq/Wk/Wv [H,D,dh] -> Wp [512,1536] (col = p*512 + h*64 + e), bias likewise
//  1. Y   = X @ Wp + bp                  [16384,1536]   (Q|K|V, head-blocked cols)
//  2. O   = causal_attention(Y)          [16384,512]    (head-concat layout)
//  3. attn= O @ Wo + bo                  [16384,512]
//  4. out1= x + LN(attn)                 [16384,512]
//  5. ff1 = relu(out1 @ W1 + b1)         [16384,2048]
//  6. ff2 = ff1 @ W2 + b2                [16384,512]
//  7. out = out1 + LN(ff2)               [16384,512] -> d_out

#define D_MODEL 512
#define N_HEADS 8
#define D_HEAD 64
#define D_FF 2048
#define NROWS 16384   // B*T

// ---------------------------------------------------------------- pack QKV
__global__ __launch_bounds__(256) void pack_qkv_kernel(
    const float* __restrict__ Wq, const float* __restrict__ Wk,
    const float* __restrict__ Wv, const float* __restrict__ bq,
    const float* __restrict__ bk, const float* __restrict__ bv,
    float* __restrict__ Wp, float* __restrict__ bp)
{
    int idx = blockIdx.x * 256 + threadIdx.x;     // over 512*1536
    if (idx >= D_MODEL * 3 * D_MODEL) return;
    int dcol = idx % (3 * D_MODEL);
    int d    = idx / (3 * D_MODEL);
    int p    = dcol / D_MODEL;
    int h    = (dcol % D_MODEL) / D_HEAD;
    int e    = dcol % D_HEAD;
    const float* W = (p == 0) ? Wq : (p == 1) ? Wk : Wv;
    Wp[idx] = W[((size_t)h * D_MODEL + d) * D_HEAD + e];
    if (d == 0) {
        const float* bb = (p == 0) ? bq : (p == 1) ? bk : bv;
        bp[dcol] = bb[h * D_HEAD + e];
    }
}

// ---------------------------------------------------------------- SGEMM
// C[M,N] = A[M,K] @ B[K,N] (+bias) (+relu). 128x128 tile, 256 threads,
// 8x8 per thread, K-chunk 16, LDS-staged with transposed A tile.
template<bool RELU, bool BIAS>
__global__ __launch_bounds__(256) void sgemm_kernel(
    const float* __restrict__ A, const float* __restrict__ B,
    const float* __restrict__ bias, float* __restrict__ C,
    int M, int N, int K)
{
    __shared__ float As[16][128 + 4];   // [k][m], pad keeps 16B alignment
    __shared__ float Bs[16][128 + 4];   // [k][n]

    const int bx = blockIdx.x;          // N tile
    const int by = blockIdx.y;          // M tile
    const int tid = threadIdx.x;
    const int tx = tid % 16;            // col group
    const int ty = tid / 16;            // row group

    float acc[8][8];
    #pragma unroll
    for (int i = 0; i < 8; ++i)
        #pragma unroll
        for (int j = 0; j < 8; ++j) acc[i][j] = 0.f;

    const float* Aptr = A + (size_t)(by * 128) * K;
    const float* Bptr = B + bx * 128;

    const int arow = tid / 4;           // 0..63 (+64)
    const int acol = (tid % 4) * 4;     // 0,4,8,12
    const int brow = tid / 32;          // 0..7 (+8)
    const int bcol = (tid % 32) * 4;    // 0..124

    for (int k0 = 0; k0 < K; k0 += 16) {
        #pragma unroll
        for (int i = 0; i < 2; ++i) {
            int r = arow + i * 64;
            float4 av = *(const float4*)(Aptr + (size_t)r * K + k0 + acol);
            As[acol + 0][r] = av.x;
            As[acol + 1][r] = av.y;
            As[acol + 2][r] = av.z;
            As[acol + 3][r] = av.w;
        }
        #pragma unroll
        for (int i = 0; i < 2; ++i) {
            int r = brow + i * 8;
            *(float4*)&Bs[r][bcol] =
                *(const float4*)(Bptr + (size_t)(k0 + r) * N + bcol);
        }
        __syncthreads();

        #pragma unroll
        for (int kk = 0; kk < 16; ++kk) {
            float a0[8], b0[8];
            *(float4*)&a0[0] = *(float4*)&As[kk][ty * 4];
            *(float4*)&a0[4] = *(float4*)&As[kk][ty * 4 + 64];
            *(float4*)&b0[0] = *(float4*)&Bs[kk][tx * 4];
            *(float4*)&b0[4] = *(float4*)&Bs[kk][tx * 4 + 64];
            #pragma unroll
            for (int i = 0; i < 8; ++i)
                #pragma unroll
                for (int j = 0; j < 8; ++j)
                    acc[i][j] = fmaf(a0[i], b0[j], acc[i][j]);
        }
        __syncthreads();
    }

    #pragma unroll
    for (int i = 0; i < 8; ++i) {
        int r = by * 128 + ty * 4 + (i & 3) + ((i >> 2) << 6);
        float* Crow = C + (size_t)r * N + bx * 128;
        #pragma unroll
        for (int jh = 0; jh < 2; ++jh) {
            int c0 = tx * 4 + jh * 64;
            float4 v;
            v.x = acc[i][jh * 4 + 0];
            v.y = acc[i][jh * 4 + 1];
            v.z = acc[i][jh * 4 + 2];
            v.w = acc[i][jh * 4 + 3];
            if (BIAS) {
                float4 bv = *(const float4*)&bias[bx * 128 + c0];
                v.x += bv.x; v.y += bv.y; v.z += bv.z; v.w += bv.w;
            }
            if (RELU) {
                v.x = fmaxf(v.x, 0.f); v.y = fmaxf(v.y, 0.f);
                v.z = fmaxf(v.z, 0.f); v.w = fmaxf(v.w, 0.f);
            }
            *(float4*)&Crow[c0] = v;
        }
    }
}

// ---------------------------------------------------------------- attention
// One block per (b*h, qtile of 64 rows). Flash-style online softmax over
// 64-key tiles, causal. Thread t owns row r=t/4, cols qq*16..+15 (qq=t%4).
__global__ __launch_bounds__(256) void attn_kernel(
    const float* __restrict__ Y,    // [NROWS, 1536] = Q|K|V head-blocked
    float* __restrict__ O)          // [NROWS, 512] head-concat
{
    __shared__ float Qs[64][68];
    __shared__ float Ks[64][68];
    __shared__ float Vs[64][68];
    __shared__ float Ps[64][68];

    const int bh = blockIdx.x;          // 0..255
    const int b  = bh >> 3;
    const int h  = bh & 7;
    const int qb = blockIdx.y;          // 0..7
    const int tid = threadIdx.x;
    const int r  = tid >> 2;            // 0..63 row within tile
    const int qq = tid & 3;             // col quarter

    const float* Yb = Y + (size_t)b * 512 * 1536;
    const int tq = qb * 64 + r;         // global query row (within seq)

    // load Q tile: row r, 16 floats per (r,qq)
    #pragma unroll
    for (int j = 0; j < 4; ++j) {
        int c = qq * 16 + j * 4;
        *(float4*)&Qs[r][c] =
            *(const float4*)(Yb + (size_t)tq * 1536 + h * 64 + c);
    }

    float m = -INFINITY, l = 0.f;
    float acc[16];
    #pragma unroll
    for (int i = 0; i < 16; ++i) acc[i] = 0.f;

    for (int kt = 0; kt <= qb; ++kt) {
        __syncthreads();                // prev PV done (also Qs on kt==0)
        #pragma unroll
        for (int j = 0; j < 4; ++j) {
            int c = qq * 16 + j * 4;
            const float* Krow = Yb + (size_t)(kt * 64 + r) * 1536 + h * 64;
            *(float4*)&Ks[r][c] = *(const float4*)(Krow + 512 + c);
            *(float4*)&Vs[r][c] = *(const float4*)(Krow + 1024 + c);
        }
        __syncthreads();

        // scores S[r][qq*16+j]
        float sacc[16];
        #pragma unroll
        for (int j = 0; j < 16; ++j) sacc[j] = 0.f;
        for (int e = 0; e < 64; e += 4) {
            float4 qv = *(float4*)&Qs[r][e];
            #pragma unroll
            for (int j = 0; j < 16; ++j) {
                float4 kv = *(float4*)&Ks[qq * 16 + j][e];
                sacc[j] += qv.x * kv.x + qv.y * kv.y + qv.z * kv.z + qv.w * kv.w;
            }
        }
        float tmax = -INFINITY;
        #pragma unroll
        for (int j = 0; j < 16; ++j) {
            float sv = sacc[j] * 0.125f;                 // 1/sqrt(64)
            int sg = kt * 64 + qq * 16 + j;
            if (sg > tq) sv = -INFINITY;                 // causal mask
            sacc[j] = sv;
            tmax = fmaxf(tmax, sv);
        }
        // row reduce across the 4 threads of row r (same wave, lanes r*4+qq)
        tmax = fmaxf(tmax, __shfl_xor(tmax, 1));
        tmax = fmaxf(tmax, __shfl_xor(tmax, 2));
        float newm = fmaxf(m, tmax);
        float corr = __expf(m - newm);
        float psum = 0.f;
        #pragma unroll
        for (int j = 0; j < 16; ++j) {
            float p = __expf(sacc[j] - newm);
            psum += p;
            Ps[r][qq * 16 + j] = p;
        }
        psum += __shfl_xor(psum, 1);
        psum += __shfl_xor(psum, 2);
        l = l * corr + psum;
        m = newm;
        #pragma unroll
        for (int i = 0; i < 16; ++i) acc[i] *= corr;

        // PV: acc[j] += sum_s Ps[r][s] * Vs[s][qq*16+j]
        // (Ps row r written by this wave's own lanes — intra-wave coherent)
        for (int s = 0; s < 64; ++s) {
            float pv = Ps[r][s];
            #pragma unroll
            for (int j4 = 0; j4 < 4; ++j4) {
                float4 vv = *(float4*)&Vs[s][qq * 16 + j4 * 4];
                acc[j4 * 4 + 0] = fmaf(pv, vv.x, acc[j4 * 4 + 0]);
                acc[j4 * 4 + 1] = fmaf(pv, vv.y, acc[j4 * 4 + 1]);
                acc[j4 * 4 + 2] = fmaf(pv, vv.z, acc[j4 * 4 + 2]);
                acc[j4 * 4 + 3] = fmaf(pv, vv.w, acc[j4 * 4 + 3]);
            }
        }
    }

    float inv = 1.0f / l;
    float* Orow = O + (size_t)(b * 512 + tq) * 512 + h * 64 + qq * 16;
    #pragma unroll
    for (int j4 = 0; j4 < 4; ++j4) {
        float4 v;
        v.x = acc[j4 * 4 + 0] * inv;
        v.y = acc[j4 * 4 + 1] * inv;
        v.z = acc[j4 * 4 + 2] * inv;
        v.w = acc[j4 * 4 + 3] * inv;
        *(float4*)&Orow[j4 * 4] = v;
    }
}

// ---------------------------------------------------------------- LN + residual
// out[row] = res[row] + (v[row]-mu)*rsqrt(var+eps)*g + b ; one wave per row.
__global__ __launch_bounds__(256) void ln_res_kernel(
    const float* __restrict__ v, const float* __restrict__ res,
    const float* __restrict__ g, const float* __restrict__ bb,
    float* __restrict__ out)
{
    int row  = blockIdx.x * 4 + (threadIdx.x >> 6);
    int lane = threadIdx.x & 63;
    const float4* vp = (const float4*)(v + (size_t)row * D_MODEL);
    float4 a = vp[lane];
    float4 c = vp[lane + 64];
    float sum = a.x + a.y + a.z + a.w + c.x + c.y + c.z + c.w;
    float sq  = a.x*a.x + a.y*a.y + a.z*a.z + a.w*a.w
              + c.x*c.x + c.y*c.y + c.z*c.z + c.w*c.w;
    #pragma unroll
    for (int o = 1; o < 64; o <<= 1) {
        sum += __shfl_xor(sum, o);
        sq  += __shfl_xor(sq, o);
    }
    float mu   = sum * (1.f / 512.f);
    float var  = sq * (1.f / 512.f) - mu * mu;
    float rstd = rsqrtf(var + 1e-5f);

    const float4* rp = (const float4*)(res + (size_t)row * D_MODEL);
    const float4* gp = (const float4*)g;
    const float4* bp = (const float4*)bb;
    float4 r0 = rp[lane], r1 = rp[lane + 64];
    float4 g0 = gp[lane], g1 = gp[lane + 64];
    float4 b0 = bp[lane], b1 = bp[lane + 64];
    float4 o0, o1;
    o0.x = r0.x + (a.x - mu) * rstd * g0.x + b0.x;
    o0.y = r0.y + (a.y - mu) * rstd * g0.y + b0.y;
    o0.z = r0.z + (a.z - mu) * rstd * g0.z + b0.z;
    o0.w = r0.w + (a.w - mu) * rstd * g0.w + b0.w;
    o1.x = r1.x + (c.x - mu) * rstd * g1.x + b1.x;
    o1.y = r1.y + (c.y - mu) * rstd * g1.y + b1.y;
    o1.z = r1.z + (c.z - mu) * rstd * g1.z + b1.z;
    o1.w = r1.w + (c.w - mu) * rstd * g1.w + b1.w;
    float4* op = (float4*)(out + (size_t)row * D_MODEL);
    op[lane] = o0;
    op[lane + 64] = o1;
}

// ---------------------------------------------------------------- launch
extern "C" void kernel_launch(void* const* d_in, const int* in_sizes, int n_in,
                              void* d_out, int out_size, void* d_ws, size_t ws_size,
                              hipStream_t stream)
{
    const float* x     = (const float*)d_in[0];
    const float* Wq    = (const float*)d_in[1];
    const float* bq    = (const float*)d_in[2];
    const float* Wk    = (const float*)d_in[3];
    const float* bk    = (const float*)d_in[4];
    const float* Wv    = (const float*)d_in[5];
    const float* bv    = (const float*)d_in[6];
    const float* Wo    = (const float*)d_in[7];
    const float* bo    = (const float*)d_in[8];
    const float* ln1_g = (const float*)d_in[9];
    const float* ln1_b = (const float*)d_in[10];
    const float* W1    = (const float*)d_in[11];
    const float* b1    = (const float*)d_in[12];
    const float* W2    = (const float*)d_in[13];
    const float* b2    = (const float*)d_in[14];
    const float* ln2_g = (const float*)d_in[15];
    const float* ln2_b = (const float*)d_in[16];

    float* ws = (float*)d_ws;
    // layout (floats):
    float* bufA = ws;                       // 33,554,432 : Y [16384,1536] then ff1 [16384,2048]
    float* Obuf = ws + 33554432;            //  8,388,608 : O, later ff2
    float* attn = ws + 41943040;            //  8,388,608
    float* out1 = ws + 50331648;            //  8,388,608
    float* Wp   = ws + 58720256;            //    786,432
    float* bp   = ws + 59506688;            //      1,536
    float* Y   = bufA;
    float* ff1 = bufA;
    float* ff2 = Obuf;

    pack_qkv_kernel<<<dim3((512 * 1536 + 255) / 256), 256, 0, stream>>>(
        Wq, Wk, Wv, bq, bk, bv, Wp, bp);

    // Y = x @ Wp + bp   [16384,1536], K=512
    sgemm_kernel<false, true><<<dim3(12, 128), 256, 0, stream>>>(
        x, Wp, bp, Y, NROWS, 1536, 512);

    // attention
    attn_kernel<<<dim3(256, 8), 256, 0, stream>>>(Y, Obuf);

    // attn = O @ Wo + bo   [16384,512], K=512
    sgemm_kernel<false, true><<<dim3(4, 128), 256, 0, stream>>>(
        Obuf, Wo, bo, attn, NROWS, 512, 512);

    // out1 = x + LN(attn)
    ln_res_kernel<<<dim3(NROWS / 4), 256, 0, stream>>>(
        attn, x, ln1_g, ln1_b, out1);

    // ff1 = relu(out1 @ W1 + b1)   [16384,2048], K=512
    sgemm_kernel<true, true><<<dim3(16, 128), 256, 0, stream>>>(
        out1, W1, b1, ff1, NROWS, 2048, 512);

    // ff2 = ff1 @ W2 + b2   [16384,512], K=2048
    sgemm_kernel<false, true><<<dim3(4, 128), 256, 0, stream>>>(
        ff1, W2, b2, ff2, NROWS, 512, 2048);

    // out = out1 + LN(ff2)
    ln_res_kernel<<<dim3(NROWS / 4), 256, 0, stream>>>(
        ff2, out1, ln2_g, ln2_b, (float*)d_out);
}

// Round 2
// 603.808 us; speedup vs baseline: 2.5876x; 2.5876x over previous
//
#include <hip/hip_runtime.h>
#include <hip/hip_bf16.h>

// Decoder block, round 2: all four GEMMs on bf16 MFMA (16x16x32), m97-style
// 128x128 tile, BK=64, global_load_lds staging, B pre-transposed [N][K].
// Attention / LayerNorm stay fp32 (target for next round).

#define D_MODEL 512
#define N_HEADS 8
#define D_HEAD 64
#define D_FF 2048
#define NROWS 16384   // B*T

typedef __bf16 bf16x8 __attribute__((ext_vector_type(8)));
typedef float f32x4 __attribute__((ext_vector_type(4)));

static __device__ __forceinline__ ushort f2bf(float f) {
    union { float f; unsigned u; } v; v.f = f;
    unsigned r = v.u + 0x7fffu + ((v.u >> 16) & 1u);   // RNE
    return (ushort)(r >> 16);
}
static __device__ __forceinline__ unsigned pack2(float lo, float hi) {
    return (unsigned)f2bf(lo) | ((unsigned)f2bf(hi) << 16);
}
static __device__ __forceinline__ void async16(const void* g, void* l) {
    __builtin_amdgcn_global_load_lds(
        (const __attribute__((address_space(1))) void*)g,
        (__attribute__((address_space(3))) void*)l, 16, 0, 0);
}

// ---------------------------------------------------------------- fp32 -> bf16
__global__ __launch_bounds__(256) void conv_bf_kernel(
    const float* __restrict__ src, ushort* __restrict__ dst, int n8)
{
    int i = blockIdx.x * 256 + threadIdx.x;
    if (i >= n8) return;
    const float4* s = (const float4*)src;
    float4 a = s[i * 2], b = s[i * 2 + 1];
    uint4 o;
    o.x = pack2(a.x, a.y); o.y = pack2(a.z, a.w);
    o.z = pack2(b.x, b.y); o.w = pack2(b.z, b.w);
    ((uint4*)dst)[i] = o;
}

// ---------------------------------------------------------------- transpose fp32[R][C] -> bf16[C][R]
// 64x64 tiles via LDS. Rd = dst row length (== R of the full matrix).
static __device__ __forceinline__ void tile_transpose_body(
    const float* __restrict__ src, int srcldc, ushort* __restrict__ dst, int Rd,
    int r0, int c0)
{
    __shared__ float t[64][65];
    int tid = threadIdx.x;
    int lr = tid >> 4, lc4 = (tid & 15) * 4;
    #pragma unroll
    for (int i = 0; i < 4; ++i) {
        float4 v = *(const float4*)&src[(size_t)(r0 + lr + i * 16) * srcldc + c0 + lc4];
        t[lr + i * 16][lc4 + 0] = v.x;
        t[lr + i * 16][lc4 + 1] = v.y;
        t[lr + i * 16][lc4 + 2] = v.z;
        t[lr + i * 16][lc4 + 3] = v.w;
    }
    __syncthreads();
    int oc = tid >> 2, orr = (tid & 3) * 16;
    uint4 u0, u1;
    u0.x = pack2(t[orr + 0][oc],  t[orr + 1][oc]);
    u0.y = pack2(t[orr + 2][oc],  t[orr + 3][oc]);
    u0.z = pack2(t[orr + 4][oc],  t[orr + 5][oc]);
    u0.w = pack2(t[orr + 6][oc],  t[orr + 7][oc]);
    u1.x = pack2(t[orr + 8][oc],  t[orr + 9][oc]);
    u1.y = pack2(t[orr + 10][oc], t[orr + 11][oc]);
    u1.z = pack2(t[orr + 12][oc], t[orr + 13][oc]);
    u1.w = pack2(t[orr + 14][oc], t[orr + 15][oc]);
    ushort* d = dst + (size_t)(c0 + oc) * Rd + r0 + orr;
    *(uint4*)&d[0] = u0;
    *(uint4*)&d[8] = u1;
}

__global__ __launch_bounds__(256) void transpose_bf_kernel(
    const float* __restrict__ src, ushort* __restrict__ dst, int R, int C)
{
    tile_transpose_body(src, C, dst, R, blockIdx.y * 64, blockIdx.x * 64);
}

// Wq/Wk/Wv [H, D, dh] -> WpT bf16 [1536][512]; row = p*512 + h*64 + e, col = d.
__global__ __launch_bounds__(256) void qkv_pack_kernel(
    const float* __restrict__ Wq, const float* __restrict__ Wk,
    const float* __restrict__ Wv, ushort* __restrict__ WpT)
{
    int z = blockIdx.z;
    int p = z >> 3, h = z & 7;
    const float* src = ((p == 0) ? Wq : (p == 1) ? Wk : Wv) + (size_t)h * D_MODEL * D_HEAD;
    ushort* dst = WpT + (size_t)(p * D_MODEL + h * D_HEAD) * D_MODEL;
    tile_transpose_body(src, D_HEAD, dst, D_MODEL, blockIdx.y * 64, 0);
}

__global__ __launch_bounds__(256) void pack_bias_kernel(
    const float* __restrict__ bq, const float* __restrict__ bk,
    const float* __restrict__ bv, float* __restrict__ bp)
{
    int idx = blockIdx.x * 256 + threadIdx.x;
    if (idx >= 3 * D_MODEL) return;
    int p = idx / D_MODEL;
    int h = (idx % D_MODEL) / D_HEAD;
    int e = idx % D_HEAD;
    const float* bb = (p == 0) ? bq : (p == 1) ? bk : bv;
    bp[idx] = bb[h * D_HEAD + e];
}

// ---------------------------------------------------------------- bf16 MFMA GEMM
// C[M][N] = A[M][K](bf16) @ BT[N][K](bf16)^T (+bias) (+relu).
// 128x128 tile, BK=64, 256 threads = 4 waves, wave -> 64x64 (4x4 fragments).
template<bool RELU, bool BIAS, bool OUT_BF16>
__global__ __launch_bounds__(256) void gemm_bf16_kernel(
    const ushort* __restrict__ A, const ushort* __restrict__ BT,
    const float* __restrict__ bias, void* __restrict__ Cout,
    int M, int N, int K)
{
    __shared__ __align__(16) __bf16 As[128 * 64];
    __shared__ __align__(16) __bf16 Bs[128 * 64];

    const int tid = threadIdx.x;
    const int w = tid >> 6, l = tid & 63;
    const int wr = w >> 1, wc = w & 1;
    const int m0 = blockIdx.y * 128, n0 = blockIdx.x * 128;

    // staging: issue i covers LDS bytes [i*4096 + w*1024 + l*16], i.e. rows
    // i*32 + w*8 + l/8, k = (l%8)*8 .. +7 (16B per lane).
    const ushort* Ag = A + (size_t)(m0 + w * 8 + l / 8) * K + (l % 8) * 8;
    const ushort* Bg = BT + (size_t)(n0 + w * 8 + l / 8) * K + (l % 8) * 8;
    __bf16* Asw = As + w * 512 + l * 8;
    __bf16* Bsw = Bs + w * 512 + l * 8;

    const int fr = l & 15, fq = l >> 4;
    const int a_base = (wr * 64 + fr) * 64 + fq * 8;
    const int b_base = (wc * 64 + fr) * 64 + fq * 8;

    f32x4 acc[4][4] = {};

    for (int k0 = 0; k0 < K; k0 += 64) {
        #pragma unroll
        for (int i = 0; i < 4; ++i) {
            async16(Ag + k0 + (size_t)i * 32 * K, Asw + i * 2048);
            async16(Bg + k0 + (size_t)i * 32 * K, Bsw + i * 2048);
        }
        __syncthreads();   // compiler drains vmcnt before barrier
        #pragma unroll
        for (int ks = 0; ks < 2; ++ks) {
            bf16x8 af[4], bfv[4];
            #pragma unroll
            for (int mi = 0; mi < 4; ++mi)
                af[mi] = *(const bf16x8*)&As[a_base + mi * 1024 + ks * 32];
            #pragma unroll
            for (int ni = 0; ni < 4; ++ni)
                bfv[ni] = *(const bf16x8*)&Bs[b_base + ni * 1024 + ks * 32];
            #pragma unroll
            for (int mi = 0; mi < 4; ++mi)
                #pragma unroll
                for (int ni = 0; ni < 4; ++ni)
                    acc[mi][ni] = __builtin_amdgcn_mfma_f32_16x16x32_bf16(
                        af[mi], bfv[ni], acc[mi][ni], 0, 0, 0);
        }
        __syncthreads();
    }

    // epilogue: D layout col=lane&15, row=(lane>>4)*4+reg (m89-verified)
    #pragma unroll
    for (int ni = 0; ni < 4; ++ni) {
        int c = n0 + wc * 64 + ni * 16 + fr;
        float bv = BIAS ? bias[c] : 0.f;
        #pragma unroll
        for (int mi = 0; mi < 4; ++mi) {
            int r0 = m0 + wr * 64 + mi * 16 + fq * 4;
            #pragma unroll
            for (int reg = 0; reg < 4; ++reg) {
                float v = acc[mi][ni][reg] + bv;
                if (RELU) v = fmaxf(v, 0.f);
                if (OUT_BF16) ((ushort*)Cout)[(size_t)(r0 + reg) * N + c] = f2bf(v);
                else          ((float*)Cout)[(size_t)(r0 + reg) * N + c] = v;
            }
        }
    }
}

// ---------------------------------------------------------------- attention (fp32, bf16 out)
__global__ __launch_bounds__(256) void attn_kernel(
    const float* __restrict__ Y,    // [NROWS, 1536] = Q|K|V head-blocked
    ushort* __restrict__ O)         // [NROWS, 512] bf16, head-concat
{
    __shared__ float Qs[64][68];
    __shared__ float Ks[64][68];
    __shared__ float Vs[64][68];
    __shared__ float Ps[64][68];

    const int bh = blockIdx.x;
    const int b  = bh >> 3;
    const int h  = bh & 7;
    const int qb = blockIdx.y;
    const int tid = threadIdx.x;
    const int r  = tid >> 2;
    const int qq = tid & 3;

    const float* Yb = Y + (size_t)b * 512 * 1536;
    const int tq = qb * 64 + r;

    #pragma unroll
    for (int j = 0; j < 4; ++j) {
        int c = qq * 16 + j * 4;
        *(float4*)&Qs[r][c] =
            *(const float4*)(Yb + (size_t)tq * 1536 + h * 64 + c);
    }

    float m = -INFINITY, l = 0.f;
    float acc[16];
    #pragma unroll
    for (int i = 0; i < 16; ++i) acc[i] = 0.f;

    for (int kt = 0; kt <= qb; ++kt) {
        __syncthreads();
        #pragma unroll
        for (int j = 0; j < 4; ++j) {
            int c = qq * 16 + j * 4;
            const float* Krow = Yb + (size_t)(kt * 64 + r) * 1536 + h * 64;
            *(float4*)&Ks[r][c] = *(const float4*)(Krow + 512 + c);
            *(float4*)&Vs[r][c] = *(const float4*)(Krow + 1024 + c);
        }
        __syncthreads();

        float sacc[16];
        #pragma unroll
        for (int j = 0; j < 16; ++j) sacc[j] = 0.f;
        for (int e = 0; e < 64; e += 4) {
            float4 qv = *(float4*)&Qs[r][e];
            #pragma unroll
            for (int j = 0; j < 16; ++j) {
                float4 kv = *(float4*)&Ks[qq * 16 + j][e];
                sacc[j] += qv.x * kv.x + qv.y * kv.y + qv.z * kv.z + qv.w * kv.w;
            }
        }
        float tmax = -INFINITY;
        #pragma unroll
        for (int j = 0; j < 16; ++j) {
            float sv = sacc[j] * 0.125f;
            int sg = kt * 64 + qq * 16 + j;
            if (sg > tq) sv = -INFINITY;
            sacc[j] = sv;
            tmax = fmaxf(tmax, sv);
        }
        tmax = fmaxf(tmax, __shfl_xor(tmax, 1));
        tmax = fmaxf(tmax, __shfl_xor(tmax, 2));
        float newm = fmaxf(m, tmax);
        float corr = __expf(m - newm);
        float psum = 0.f;
        #pragma unroll
        for (int j = 0; j < 16; ++j) {
            float p = __expf(sacc[j] - newm);
            psum += p;
            Ps[r][qq * 16 + j] = p;
        }
        psum += __shfl_xor(psum, 1);
        psum += __shfl_xor(psum, 2);
        l = l * corr + psum;
        m = newm;
        #pragma unroll
        for (int i = 0; i < 16; ++i) acc[i] *= corr;

        for (int s = 0; s < 64; ++s) {
            float pv = Ps[r][s];
            #pragma unroll
            for (int j4 = 0; j4 < 4; ++j4) {
                float4 vv = *(float4*)&Vs[s][qq * 16 + j4 * 4];
                acc[j4 * 4 + 0] = fmaf(pv, vv.x, acc[j4 * 4 + 0]);
                acc[j4 * 4 + 1] = fmaf(pv, vv.y, acc[j4 * 4 + 1]);
                acc[j4 * 4 + 2] = fmaf(pv, vv.z, acc[j4 * 4 + 2]);
                acc[j4 * 4 + 3] = fmaf(pv, vv.w, acc[j4 * 4 + 3]);
            }
        }
    }

    float inv = 1.0f / l;
    ushort* Orow = O + (size_t)(b * 512 + tq) * 512 + h * 64 + qq * 16;
    uint4 u0, u1;
    u0.x = pack2(acc[0] * inv,  acc[1] * inv);
    u0.y = pack2(acc[2] * inv,  acc[3] * inv);
    u0.z = pack2(acc[4] * inv,  acc[5] * inv);
    u0.w = pack2(acc[6] * inv,  acc[7] * inv);
    u1.x = pack2(acc[8] * inv,  acc[9] * inv);
    u1.y = pack2(acc[10] * inv, acc[11] * inv);
    u1.z = pack2(acc[12] * inv, acc[13] * inv);
    u1.w = pack2(acc[14] * inv, acc[15] * inv);
    *(uint4*)&Orow[0] = u0;
    *(uint4*)&Orow[8] = u1;
}

// ---------------------------------------------------------------- LN + residual
template<bool WBF>
__global__ __launch_bounds__(256) void ln_res_kernel(
    const float* __restrict__ v, const float* __restrict__ res,
    const float* __restrict__ g, const float* __restrict__ bb,
    float* __restrict__ out, ushort* __restrict__ out_bf)
{
    int row  = blockIdx.x * 4 + (threadIdx.x >> 6);
    int lane = threadIdx.x & 63;
    const float4* vp = (const float4*)(v + (size_t)row * D_MODEL);
    float4 a = vp[lane];
    float4 c = vp[lane + 64];
    float sum = a.x + a.y + a.z + a.w + c.x + c.y + c.z + c.w;
    float sq  = a.x*a.x + a.y*a.y + a.z*a.z + a.w*a.w
              + c.x*c.x + c.y*c.y + c.z*c.z + c.w*c.w;
    #pragma unroll
    for (int o = 1; o < 64; o <<= 1) {
        sum += __shfl_xor(sum, o);
        sq  += __shfl_xor(sq, o);
    }
    float mu   = sum * (1.f / 512.f);
    float var  = sq * (1.f / 512.f) - mu * mu;
    float rstd = rsqrtf(var + 1e-5f);

    const float4* rp = (const float4*)(res + (size_t)row * D_MODEL);
    const float4* gp = (const float4*)g;
    const float4* bp = (const float4*)bb;
    float4 r0 = rp[lane], r1 = rp[lane + 64];
    float4 g0 = gp[lane], g1 = gp[lane + 64];
    float4 b0 = bp[lane], b1 = bp[lane + 64];
    float4 o0, o1;
    o0.x = r0.x + (a.x - mu) * rstd * g0.x + b0.x;
    o0.y = r0.y + (a.y - mu) * rstd * g0.y + b0.y;
    o0.z = r0.z + (a.z - mu) * rstd * g0.z + b0.z;
    o0.w = r0.w + (a.w - mu) * rstd * g0.w + b0.w;
    o1.x = r1.x + (c.x - mu) * rstd * g1.x + b1.x;
    o1.y = r1.y + (c.y - mu) * rstd * g1.y + b1.y;
    o1.z = r1.z + (c.z - mu) * rstd * g1.z + b1.z;
    o1.w = r1.w + (c.w - mu) * rstd * g1.w + b1.w;
    float4* op = (float4*)(out + (size_t)row * D_MODEL);
    op[lane] = o0;
    op[lane + 64] = o1;
    if (WBF) {
        uint2 p0, p1;
        p0.x = pack2(o0.x, o0.y); p0.y = pack2(o0.z, o0.w);
        p1.x = pack2(o1.x, o1.y); p1.y = pack2(o1.z, o1.w);
        *(uint2*)&out_bf[(size_t)row * D_MODEL + lane * 4] = p0;
        *(uint2*)&out_bf[(size_t)row * D_MODEL + 256 + lane * 4] = p1;
    }
}

// ---------------------------------------------------------------- launch
extern "C" void kernel_launch(void* const* d_in, const int* in_sizes, int n_in,
                              void* d_out, int out_size, void* d_ws, size_t ws_size,
                              hipStream_t stream)
{
    const float* x     = (const float*)d_in[0];
    const float* Wq    = (const float*)d_in[1];
    const float* bq    = (const float*)d_in[2];
    const float* Wk    = (const float*)d_in[3];
    const float* bk    = (const float*)d_in[4];
    const float* Wv    = (const float*)d_in[5];
    const float* bv    = (const float*)d_in[6];
    const float* Wo    = (const float*)d_in[7];
    const float* bo    = (const float*)d_in[8];
    const float* ln1_g = (const float*)d_in[9];
    const float* ln1_b = (const float*)d_in[10];
    const float* W1    = (const float*)d_in[11];
    const float* b1    = (const float*)d_in[12];
    const float* W2    = (const float*)d_in[13];
    const float* b2    = (const float*)d_in[14];
    const float* ln2_g = (const float*)d_in[15];
    const float* ln2_b = (const float*)d_in[16];

    float* ws = (float*)d_ws;
    // layout (float-slot offsets)
    float*  Y       = ws;                          // 25,165,824  [16384,1536] fp32 (ff1_bf aliases)
    float*  attnb   = ws + 25165824;               //  8,388,608  (ff2 aliases)
    float*  out1    = ws + 33554432;               //  8,388,608
    ushort* x_bf    = (ushort*)(ws + 41943040);    //  8,388,608 ushorts
    ushort* O_bf    = (ushort*)(ws + 46137344);    //  8,388,608 ushorts
    ushort* out1_bf = (ushort*)(ws + 50331648);    //  8,388,608 ushorts
    ushort* WpT     = (ushort*)(ws + 54525952);    //  1536*512
    ushort* WoT     = (ushort*)(ws + 54919168);    //  512*512
    ushort* W1T     = (ushort*)(ws + 55050240);    //  2048*512
    ushort* W2T     = (ushort*)(ws + 55574528);    //  512*2048
    float*  bp      = ws + 56098816;               //  1536
    ushort* ff1_bf  = (ushort*)Y;                  //  16384*2048 ushorts (fits in Y)
    float*  ff2     = attnb;

    // weight prep + activation conversion
    conv_bf_kernel<<<dim3(4096), 256, 0, stream>>>(x, x_bf, NROWS * D_MODEL / 8);
    qkv_pack_kernel<<<dim3(1, 8, 24), 256, 0, stream>>>(Wq, Wk, Wv, WpT);
    transpose_bf_kernel<<<dim3(8, 8), 256, 0, stream>>>(Wo, WoT, 512, 512);
    transpose_bf_kernel<<<dim3(32, 8), 256, 0, stream>>>(W1, W1T, 512, 2048);
    transpose_bf_kernel<<<dim3(8, 32), 256, 0, stream>>>(W2, W2T, 2048, 512);
    pack_bias_kernel<<<dim3(6), 256, 0, stream>>>(bq, bk, bv, bp);

    // Y = x @ Wp + bp   [16384,1536] fp32
    gemm_bf16_kernel<false, true, false><<<dim3(12, 128), 256, 0, stream>>>(
        x_bf, WpT, bp, Y, NROWS, 1536, 512);

    // attention -> O_bf (bf16)
    attn_kernel<<<dim3(256, 8), 256, 0, stream>>>(Y, O_bf);

    // attn = O @ Wo + bo   [16384,512] fp32
    gemm_bf16_kernel<false, true, false><<<dim3(4, 128), 256, 0, stream>>>(
        O_bf, WoT, bo, attnb, NROWS, 512, 512);

    // out1 = x + LN(attn); also bf16 copy
    ln_res_kernel<true><<<dim3(NROWS / 4), 256, 0, stream>>>(
        attnb, x, ln1_g, ln1_b, out1, out1_bf);

    // ff1 = relu(out1 @ W1 + b1) -> bf16 [16384,2048]
    gemm_bf16_kernel<true, true, true><<<dim3(16, 128), 256, 0, stream>>>(
        out1_bf, W1T, b1, ff1_bf, NROWS, 2048, 512);

    // ff2 = ff1 @ W2 + b2   [16384,512] fp32
    gemm_bf16_kernel<false, true, false><<<dim3(4, 128), 256, 0, stream>>>(
        ff1_bf, W2T, b2, ff2, NROWS, 512, 2048);

    // out = out1 + LN(ff2)
    ln_res_kernel<false><<<dim3(NROWS / 4), 256, 0, stream>>>(
        ff2, out1, ln2_g, ln2_b, (float*)d_out, nullptr);
}

// Round 3
// 263.974 us; speedup vs baseline: 5.9188x; 2.2874x over previous
//
#include <hip/hip_runtime.h>
#include <hip/hip_bf16.h>

// Decoder block, round 3: GEMMs on bf16 MFMA (128x128, BK=64, global_load_lds)
// + MFMA flash attention (swapped QK^T, XOR-swizzled LDS, V pre-transposed by
// the QKV GEMM epilogue).

#define D_MODEL 512
#define N_HEADS 8
#define D_HEAD 64
#define D_FF 2048
#define NROWS 16384   // B*T

typedef __bf16 bf16x8 __attribute__((ext_vector_type(8)));
typedef float f32x4 __attribute__((ext_vector_type(4)));

// XOR swizzle within a 128B-row tile: involution, bits 4-6 ^= row&7.
#define SWZ(x) ((x) ^ ((((x) >> 7) & 7) << 4))

static __device__ __forceinline__ ushort f2bf(float f) {
    union { float f; unsigned u; } v; v.f = f;
    unsigned r = v.u + 0x7fffu + ((v.u >> 16) & 1u);   // RNE
    return (ushort)(r >> 16);
}
static __device__ __forceinline__ unsigned pack2(float lo, float hi) {
    return (unsigned)f2bf(lo) | ((unsigned)f2bf(hi) << 16);
}
static __device__ __forceinline__ void async16(const void* g, void* l) {
    __builtin_amdgcn_global_load_lds(
        (const __attribute__((address_space(1))) void*)g,
        (__attribute__((address_space(3))) void*)l, 16, 0, 0);
}

// ---------------------------------------------------------------- fp32 -> bf16
__global__ __launch_bounds__(256) void conv_bf_kernel(
    const float* __restrict__ src, ushort* __restrict__ dst, int n8)
{
    int i = blockIdx.x * 256 + threadIdx.x;
    if (i >= n8) return;
    const float4* s = (const float4*)src;
    float4 a = s[i * 2], b = s[i * 2 + 1];
    uint4 o;
    o.x = pack2(a.x, a.y); o.y = pack2(a.z, a.w);
    o.z = pack2(b.x, b.y); o.w = pack2(b.z, b.w);
    ((uint4*)dst)[i] = o;
}

// ---------------------------------------------------------------- transpose fp32[R][C] -> bf16[C][R]
static __device__ __forceinline__ void tile_transpose_body(
    const float* __restrict__ src, int srcldc, ushort* __restrict__ dst, int Rd,
    int r0, int c0)
{
    __shared__ float t[64][65];
    int tid = threadIdx.x;
    int lr = tid >> 4, lc4 = (tid & 15) * 4;
    #pragma unroll
    for (int i = 0; i < 4; ++i) {
        float4 v = *(const float4*)&src[(size_t)(r0 + lr + i * 16) * srcldc + c0 + lc4];
        t[lr + i * 16][lc4 + 0] = v.x;
        t[lr + i * 16][lc4 + 1] = v.y;
        t[lr + i * 16][lc4 + 2] = v.z;
        t[lr + i * 16][lc4 + 3] = v.w;
    }
    __syncthreads();
    int oc = tid >> 2, orr = (tid & 3) * 16;
    uint4 u0, u1;
    u0.x = pack2(t[orr + 0][oc],  t[orr + 1][oc]);
    u0.y = pack2(t[orr + 2][oc],  t[orr + 3][oc]);
    u0.z = pack2(t[orr + 4][oc],  t[orr + 5][oc]);
    u0.w = pack2(t[orr + 6][oc],  t[orr + 7][oc]);
    u1.x = pack2(t[orr + 8][oc],  t[orr + 9][oc]);
    u1.y = pack2(t[orr + 10][oc], t[orr + 11][oc]);
    u1.z = pack2(t[orr + 12][oc], t[orr + 13][oc]);
    u1.w = pack2(t[orr + 14][oc], t[orr + 15][oc]);
    ushort* d = dst + (size_t)(c0 + oc) * Rd + r0 + orr;
    *(uint4*)&d[0] = u0;
    *(uint4*)&d[8] = u1;
}

__global__ __launch_bounds__(256) void transpose_bf_kernel(
    const float* __restrict__ src, ushort* __restrict__ dst, int R, int C)
{
    tile_transpose_body(src, C, dst, R, blockIdx.y * 64, blockIdx.x * 64);
}

// Wq/Wk/Wv [H, D, dh] -> WpT bf16 [1536][512]; row = p*512 + h*64 + e, col = d.
__global__ __launch_bounds__(256) void qkv_pack_kernel(
    const float* __restrict__ Wq, const float* __restrict__ Wk,
    const float* __restrict__ Wv, ushort* __restrict__ WpT)
{
    int z = blockIdx.z;
    int p = z >> 3, h = z & 7;
    const float* src = ((p == 0) ? Wq : (p == 1) ? Wk : Wv) + (size_t)h * D_MODEL * D_HEAD;
    ushort* dst = WpT + (size_t)(p * D_MODEL + h * D_HEAD) * D_MODEL;
    tile_transpose_body(src, D_HEAD, dst, D_MODEL, blockIdx.y * 64, 0);
}

__global__ __launch_bounds__(256) void pack_bias_kernel(
    const float* __restrict__ bq, const float* __restrict__ bk,
    const float* __restrict__ bv, float* __restrict__ bp)
{
    int idx = blockIdx.x * 256 + threadIdx.x;
    if (idx >= 3 * D_MODEL) return;
    int p = idx / D_MODEL;
    int h = (idx % D_MODEL) / D_HEAD;
    int e = idx % D_HEAD;
    const float* bb = (p == 0) ? bq : (p == 1) ? bk : bv;
    bp[idx] = bb[h * D_HEAD + e];
}

// ---------------------------------------------------------------- bf16 MFMA GEMM
// C = A[M,K] @ BT[N,K]^T (+bias) (+relu). OMODE: 0=f32 out, 1=bf16 out,
// 2=QKV split (Qg/Kg natural [bh][t][e], Vt transposed [bh][e][t]).
template<int OMODE, bool RELU>
__global__ __launch_bounds__(256) void gemm_bf16_kernel(
    const ushort* __restrict__ A, const ushort* __restrict__ BT,
    const float* __restrict__ bias, void* __restrict__ Cout,
    ushort* __restrict__ Qg, ushort* __restrict__ Kg, ushort* __restrict__ Vt,
    int M, int N, int K)
{
    __shared__ __align__(16) __bf16 As[128 * 64];
    __shared__ __align__(16) __bf16 Bs[128 * 64];

    const int tid = threadIdx.x;
    const int w = tid >> 6, l = tid & 63;
    const int wr = w >> 1, wc = w & 1;
    const int m0 = blockIdx.y * 128, n0 = blockIdx.x * 128;

    const ushort* Ag = A + (size_t)(m0 + w * 8 + l / 8) * K + (l % 8) * 8;
    const ushort* Bg = BT + (size_t)(n0 + w * 8 + l / 8) * K + (l % 8) * 8;
    __bf16* Asw = As + w * 512 + l * 8;
    __bf16* Bsw = Bs + w * 512 + l * 8;

    const int fr = l & 15, fq = l >> 4;
    const int a_base = (wr * 64 + fr) * 64 + fq * 8;
    const int b_base = (wc * 64 + fr) * 64 + fq * 8;

    f32x4 acc[4][4] = {};

    for (int k0 = 0; k0 < K; k0 += 64) {
        #pragma unroll
        for (int i = 0; i < 4; ++i) {
            async16(Ag + k0 + (size_t)i * 32 * K, Asw + i * 2048);
            async16(Bg + k0 + (size_t)i * 32 * K, Bsw + i * 2048);
        }
        __syncthreads();
        #pragma unroll
        for (int ks = 0; ks < 2; ++ks) {
            bf16x8 af[4], bfv[4];
            #pragma unroll
            for (int mi = 0; mi < 4; ++mi)
                af[mi] = *(const bf16x8*)&As[a_base + mi * 1024 + ks * 32];
            #pragma unroll
            for (int ni = 0; ni < 4; ++ni)
                bfv[ni] = *(const bf16x8*)&Bs[b_base + ni * 1024 + ks * 32];
            #pragma unroll
            for (int mi = 0; mi < 4; ++mi)
                #pragma unroll
                for (int ni = 0; ni < 4; ++ni)
                    acc[mi][ni] = __builtin_amdgcn_mfma_f32_16x16x32_bf16(
                        af[mi], bfv[ni], acc[mi][ni], 0, 0, 0);
        }
        __syncthreads();
    }

    // epilogue: D layout col=lane&15, row=(lane>>4)*4+reg
    #pragma unroll
    for (int ni = 0; ni < 4; ++ni) {
        int c = n0 + wc * 64 + ni * 16 + fr;
        float bv = bias ? bias[c] : 0.f;
        #pragma unroll
        for (int mi = 0; mi < 4; ++mi) {
            int r0 = m0 + wr * 64 + mi * 16 + fq * 4;
            float vv[4];
            #pragma unroll
            for (int reg = 0; reg < 4; ++reg) {
                float v = acc[mi][ni][reg] + bv;
                if (RELU) v = fmaxf(v, 0.f);
                vv[reg] = v;
            }
            if (OMODE == 0) {
                #pragma unroll
                for (int reg = 0; reg < 4; ++reg)
                    ((float*)Cout)[(size_t)(r0 + reg) * N + c] = vv[reg];
            } else if (OMODE == 1) {
                #pragma unroll
                for (int reg = 0; reg < 4; ++reg)
                    ((ushort*)Cout)[(size_t)(r0 + reg) * N + c] = f2bf(vv[reg]);
            } else {
                int p = n0 >> 9;                // uniform per block
                int h = (c >> 6) & 7, e = c & 63;
                int b = r0 >> 9, t0 = r0 & 511;
                size_t bh = (size_t)(b * 8 + h);
                if (p == 2) {
                    uint2 pk;
                    pk.x = pack2(vv[0], vv[1]);
                    pk.y = pack2(vv[2], vv[3]);
                    *(uint2*)&Vt[bh * 32768 + (size_t)e * 512 + t0] = pk;
                } else {
                    ushort* dst = (p == 0 ? Qg : Kg) + bh * 32768 + (size_t)t0 * 64 + e;
                    #pragma unroll
                    for (int reg = 0; reg < 4; ++reg)
                        dst[reg * 64] = f2bf(vv[reg]);
                }
            }
        }
    }
}

// ---------------------------------------------------------------- MFMA attention
// Block = 256 thr (4 waves), one (b,h) x 64-row Q tile. Swapped QK^T (S^T =
// K@Q^T) -> softmax nearly lane-local; P^T -> wave-private LDS strip (aliases
// dead Q tile) -> PV with Vt as B-operand. K/V double-buffered, one barrier
// per tile. All LDS tiles XOR-swizzled via pre-swizzled global source.
__global__ __launch_bounds__(256) void attn_kernel(
    const ushort* __restrict__ Qg,   // [bh][t][e]
    const ushort* __restrict__ Kg,   // [bh][t][e]
    const ushort* __restrict__ Vt,   // [bh][e][t]
    ushort* __restrict__ O)          // [b*512+t][h*64+e]
{
    __shared__ __align__(16) char QP[8192];       // Q tile, then P strips
    __shared__ __align__(16) char KB[2][8192];
    __shared__ __align__(16) char VB[2][8192];

    const int bh = blockIdx.x, qb = blockIdx.y;
    const int tid = threadIdx.x;
    const int w = tid >> 6, l = tid & 63;

    const ushort* Qb = Qg + (size_t)bh * 32768;
    const ushort* Kb = Kg + (size_t)bh * 32768;
    const ushort* Vb = Vt + (size_t)bh * 32768;

    // stage Q tile (linear LDS dest, swizzled global source)
    #pragma unroll
    for (int i = 0; i < 2; ++i) {
        int Xi = i * 4096 + tid * 16;
        int row = Xi >> 7;
        int sw = SWZ(Xi) & 127;
        async16((const char*)(Qb + (size_t)(qb * 64 + row) * 64) + sw, QP + Xi);
    }
    #define STAGEKV(kt, bb)                                                     \
        { _Pragma("unroll")                                                     \
          for (int i = 0; i < 2; ++i) {                                         \
              int Xi = i * 4096 + tid * 16;                                     \
              int row = Xi >> 7;                                                \
              int sw = SWZ(Xi) & 127;                                           \
              async16((const char*)(Kb + (size_t)((kt) * 64 + row) * 64) + sw,  \
                      KB[bb] + Xi);                                             \
              async16((const char*)(Vb + (size_t)row * 512 + (kt) * 64) + sw,   \
                      VB[bb] + Xi);                                             \
          } }
    STAGEKV(0, 0);
    __syncthreads();

    // hoist Q fragments (B-frag: col = qrow = w*16 + (l&15), k contiguous)
    bf16x8 qf[2];
    {
        int qrow = w * 16 + (l & 15);
        #pragma unroll
        for (int ks = 0; ks < 2; ++ks) {
            int X = qrow * 128 + ks * 64 + (l >> 4) * 16;
            qf[ks] = *(const bf16x8*)(QP + SWZ(X));
        }
    }

    float mrow = -INFINITY, lrow = 0.f;   // softmax state for qrow = w*16+(l&15)
    f32x4 oacc[4] = {};                    // O: col dh = n*16+(l&15), rows (l>>4)*4+reg

    for (int kt = 0; kt <= qb; ++kt) {
        int cur = kt & 1;
        if (kt < qb) STAGEKV(kt + 1, cur ^ 1);

        // S^T = K @ Q^T  (A = K rows = keys, B = Q cols = qrows)
        f32x4 sacc[4] = {};
        #pragma unroll
        for (int ks = 0; ks < 2; ++ks) {
            #pragma unroll
            for (int mi = 0; mi < 4; ++mi) {
                int X = (mi * 16 + (l & 15)) * 128 + ks * 64 + (l >> 4) * 16;
                bf16x8 kf = *(const bf16x8*)(KB[cur] + SWZ(X));
                sacc[mi] = __builtin_amdgcn_mfma_f32_16x16x32_bf16(
                    kf, qf[ks], sacc[mi], 0, 0, 0);
            }
        }

        // online softmax: lane owns 16 keys of one qrow
        float sv[16];
        float tmax = -INFINITY;
        const int qrow_t = w * 16 + (l & 15);
        #pragma unroll
        for (int mi = 0; mi < 4; ++mi)
            #pragma unroll
            for (int r = 0; r < 4; ++r) {
                float s = sacc[mi][r] * 0.125f;
                if (kt == qb) {
                    int key_l = mi * 16 + (l >> 4) * 4 + r;
                    if (key_l > qrow_t) s = -INFINITY;
                }
                sv[mi * 4 + r] = s;
                tmax = fmaxf(tmax, s);
            }
        tmax = fmaxf(tmax, __shfl_xor(tmax, 16));
        tmax = fmaxf(tmax, __shfl_xor(tmax, 32));
        float mnew = fmaxf(mrow, tmax);
        float corr = __expf(mrow - mnew);
        mrow = mnew;
        float psum = 0.f;
        #pragma unroll
        for (int i = 0; i < 16; ++i) { sv[i] = __expf(sv[i] - mnew); psum += sv[i]; }
        psum += __shfl_xor(psum, 16);
        psum += __shfl_xor(psum, 32);
        lrow = lrow * corr + psum;

        // P^T -> wave-private strip of QP (rows w*16..w*16+15)
        #pragma unroll
        for (int mi = 0; mi < 4; ++mi) {
            uint2 pk;
            pk.x = pack2(sv[mi * 4 + 0], sv[mi * 4 + 1]);
            pk.y = pack2(sv[mi * 4 + 2], sv[mi * 4 + 3]);
            int X = qrow_t * 128 + (mi * 16 + (l >> 4) * 4) * 2;
            *(uint2*)(QP + SWZ(X)) = pk;
        }

        // rescale O (corr redistributed to O-row lanes)
        #pragma unroll
        for (int r = 0; r < 4; ++r) {
            float cr = __shfl(corr, (l & 48) | ((l >> 4) * 4 + r));
            #pragma unroll
            for (int n = 0; n < 4; ++n) oacc[n][r] *= cr;
        }

        // PV: A = P strip, B = Vt tile
        #pragma unroll
        for (int ks = 0; ks < 2; ++ks) {
            int Xa = qrow_t * 128 + ks * 64 + (l >> 4) * 16;
            bf16x8 pa = *(const bf16x8*)(QP + SWZ(Xa));
            #pragma unroll
            for (int n = 0; n < 4; ++n) {
                int Xb = (n * 16 + (l & 15)) * 128 + ks * 64 + (l >> 4) * 16;
                bf16x8 vb = *(const bf16x8*)(VB[cur] + SWZ(Xb));
                oacc[n] = __builtin_amdgcn_mfma_f32_16x16x32_bf16(
                    pa, vb, oacc[n], 0, 0, 0);
            }
        }
        __syncthreads();   // all waves done with KB/VB[cur]; next stage landed
    }

    // epilogue: O rows = w*16 + (l>>4)*4 + r, col = h*64 + n*16 + (l&15)
    float linv = 1.0f / lrow;
    const int b_ = bh >> 3, h_ = bh & 7;
    #pragma unroll
    for (int r = 0; r < 4; ++r) {
        float li = __shfl(linv, (l & 48) | ((l >> 4) * 4 + r));
        int trow = qb * 64 + w * 16 + (l >> 4) * 4 + r;
        size_t obase = ((size_t)b_ * 512 + trow) * 512 + h_ * 64 + (l & 15);
        #pragma unroll
        for (int n = 0; n < 4; ++n)
            O[obase + n * 16] = f2bf(oacc[n][r] * li);
    }
}

// ---------------------------------------------------------------- LN + residual
template<bool WBF>
__global__ __launch_bounds__(256) void ln_res_kernel(
    const float* __restrict__ v, const float* __restrict__ res,
    const float* __restrict__ g, const float* __restrict__ bb,
    float* __restrict__ out, ushort* __restrict__ out_bf)
{
    int row  = blockIdx.x * 4 + (threadIdx.x >> 6);
    int lane = threadIdx.x & 63;
    const float4* vp = (const float4*)(v + (size_t)row * D_MODEL);
    float4 a = vp[lane];
    float4 c = vp[lane + 64];
    float sum = a.x + a.y + a.z + a.w + c.x + c.y + c.z + c.w;
    float sq  = a.x*a.x + a.y*a.y + a.z*a.z + a.w*a.w
              + c.x*c.x + c.y*c.y + c.z*c.z + c.w*c.w;
    #pragma unroll
    for (int o = 1; o < 64; o <<= 1) {
        sum += __shfl_xor(sum, o);
        sq  += __shfl_xor(sq, o);
    }
    float mu   = sum * (1.f / 512.f);
    float var  = sq * (1.f / 512.f) - mu * mu;
    float rstd = rsqrtf(var + 1e-5f);

    const float4* rp = (const float4*)(res + (size_t)row * D_MODEL);
    const float4* gp = (const float4*)g;
    const float4* bp = (const float4*)bb;
    float4 r0 = rp[lane], r1 = rp[lane + 64];
    float4 g0 = gp[lane], g1 = gp[lane + 64];
    float4 b0 = bp[lane], b1 = bp[lane + 64];
    float4 o0, o1;
    o0.x = r0.x + (a.x - mu) * rstd * g0.x + b0.x;
    o0.y = r0.y + (a.y - mu) * rstd * g0.y + b0.y;
    o0.z = r0.z + (a.z - mu) * rstd * g0.z + b0.z;
    o0.w = r0.w + (a.w - mu) * rstd * g0.w + b0.w;
    o1.x = r1.x + (c.x - mu) * rstd * g1.x + b1.x;
    o1.y = r1.y + (c.y - mu) * rstd * g1.y + b1.y;
    o1.z = r1.z + (c.z - mu) * rstd * g1.z + b1.z;
    o1.w = r1.w + (c.w - mu) * rstd * g1.w + b1.w;
    float4* op = (float4*)(out + (size_t)row * D_MODEL);
    op[lane] = o0;
    op[lane + 64] = o1;
    if (WBF) {
        uint2 p0, p1;
        p0.x = pack2(o0.x, o0.y); p0.y = pack2(o0.z, o0.w);
        p1.x = pack2(o1.x, o1.y); p1.y = pack2(o1.z, o1.w);
        *(uint2*)&out_bf[(size_t)row * D_MODEL + lane * 4] = p0;
        *(uint2*)&out_bf[(size_t)row * D_MODEL + 256 + lane * 4] = p1;
    }
}

// ---------------------------------------------------------------- launch
extern "C" void kernel_launch(void* const* d_in, const int* in_sizes, int n_in,
                              void* d_out, int out_size, void* d_ws, size_t ws_size,
                              hipStream_t stream)
{
    const float* x     = (const float*)d_in[0];
    const float* Wq    = (const float*)d_in[1];
    const float* bq    = (const float*)d_in[2];
    const float* Wk    = (const float*)d_in[3];
    const float* bk    = (const float*)d_in[4];
    const float* Wv    = (const float*)d_in[5];
    const float* bv    = (const float*)d_in[6];
    const float* Wo    = (const float*)d_in[7];
    const float* bo    = (const float*)d_in[8];
    const float* ln1_g = (const float*)d_in[9];
    const float* ln1_b = (const float*)d_in[10];
    const float* W1    = (const float*)d_in[11];
    const float* b1    = (const float*)d_in[12];
    const float* W2    = (const float*)d_in[13];
    const float* b2    = (const float*)d_in[14];
    const float* ln2_g = (const float*)d_in[15];
    const float* ln2_b = (const float*)d_in[16];

    float* ws = (float*)d_ws;
    // float-slot layout (ff1_bf aliases Qg..O_bf, all dead by FFN time)
    ushort* Qg      = (ushort*)(ws);               // 8,388,608 us
    ushort* Kg      = (ushort*)(ws + 4194304);     // 8,388,608 us
    ushort* Vt      = (ushort*)(ws + 8388608);     // 8,388,608 us
    ushort* O_bf    = (ushort*)(ws + 12582912);    // 8,388,608 us
    float*  attnb   = ws + 16777216;               // 8,388,608 f32 (ff2 aliases)
    float*  out1    = ws + 25165824;               // 8,388,608 f32
    ushort* out1_bf = (ushort*)(ws + 33554432);    // 8,388,608 us
    ushort* x_bf    = (ushort*)(ws + 37748736);    // 8,388,608 us
    ushort* WpT     = (ushort*)(ws + 41943040);    // 786,432 us
    ushort* WoT     = (ushort*)(ws + 42336256);    // 262,144 us
    ushort* W1T     = (ushort*)(ws + 42467328);    // 1,048,576 us
    ushort* W2T     = (ushort*)(ws + 42991616);    // 1,048,576 us
    float*  bp      = ws + 43515904;               // 1,536 f32
    ushort* ff1_bf  = (ushort*)ws;                 // 33,554,432 us (alias)
    float*  ff2     = attnb;

    conv_bf_kernel<<<dim3(4096), 256, 0, stream>>>(x, x_bf, NROWS * D_MODEL / 8);
    qkv_pack_kernel<<<dim3(1, 8, 24), 256, 0, stream>>>(Wq, Wk, Wv, WpT);
    transpose_bf_kernel<<<dim3(8, 8), 256, 0, stream>>>(Wo, WoT, 512, 512);
    transpose_bf_kernel<<<dim3(32, 8), 256, 0, stream>>>(W1, W1T, 512, 2048);
    transpose_bf_kernel<<<dim3(8, 32), 256, 0, stream>>>(W2, W2T, 2048, 512);
    pack_bias_kernel<<<dim3(6), 256, 0, stream>>>(bq, bk, bv, bp);

    // QKV: x @ Wp + bp -> Qg/Kg natural, Vt transposed
    gemm_bf16_kernel<2, false><<<dim3(12, 128), 256, 0, stream>>>(
        x_bf, WpT, bp, nullptr, Qg, Kg, Vt, NROWS, 1536, 512);

    // attention -> O_bf
    attn_kernel<<<dim3(256, 8), 256, 0, stream>>>(Qg, Kg, Vt, O_bf);

    // attn = O @ Wo + bo  (fp32 out)
    gemm_bf16_kernel<0, false><<<dim3(4, 128), 256, 0, stream>>>(
        O_bf, WoT, bo, attnb, nullptr, nullptr, nullptr, NROWS, 512, 512);

    // out1 = x + LN(attn); + bf16 copy
    ln_res_kernel<true><<<dim3(NROWS / 4), 256, 0, stream>>>(
        attnb, x, ln1_g, ln1_b, out1, out1_bf);

    // ff1 = relu(out1 @ W1 + b1) -> bf16
    gemm_bf16_kernel<1, true><<<dim3(16, 128), 256, 0, stream>>>(
        out1_bf, W1T, b1, ff1_bf, nullptr, nullptr, nullptr, NROWS, 2048, 512);

    // ff2 = ff1 @ W2 + b2  (fp32 out)
    gemm_bf16_kernel<0, false><<<dim3(4, 128), 256, 0, stream>>>(
        ff1_bf, W2T, b2, ff2, nullptr, nullptr, nullptr, NROWS, 512, 2048);

    // out = out1 + LN(ff2)
    ln_res_kernel<false><<<dim3(NROWS / 4), 256, 0, stream>>>(
        ff2, out1, ln2_g, ln2_b, (float*)d_out, nullptr);
}

// Round 4
// 223.983 us; speedup vs baseline: 6.9756x; 1.1785x over previous
//
#include <hip/hip_runtime.h>
#include <hip/hip_bf16.h>

// Decoder block, round 4: GEMM rebuilt around mfma_32x32x16, BM256xBN128,
// 2-deep LDS dbuf with counted vmcnt + raw barrier, T2 LDS swizzle, T1 XCD
// swizzle. Attention / LN / prep unchanged from round 3 (passing).

#define D_MODEL 512
#define N_HEADS 8
#define D_HEAD 64
#define D_FF 2048
#define NROWS 16384   // B*T

typedef __bf16 bf16x8 __attribute__((ext_vector_type(8)));
typedef float f32x4 __attribute__((ext_vector_type(4)));
typedef float f32x16 __attribute__((ext_vector_type(16)));

// XOR swizzle within a 128B-row tile: involution, bits 4-6 ^= row&7.
#define SWZ(x) ((x) ^ ((((x) >> 7) & 7) << 4))

static __device__ __forceinline__ ushort f2bf(float f) {
    union { float f; unsigned u; } v; v.f = f;
    unsigned r = v.u + 0x7fffu + ((v.u >> 16) & 1u);   // RNE
    return (ushort)(r >> 16);
}
static __device__ __forceinline__ unsigned pack2(float lo, float hi) {
    return (unsigned)f2bf(lo) | ((unsigned)f2bf(hi) << 16);
}
static __device__ __forceinline__ void async16(const void* g, void* l) {
    __builtin_amdgcn_global_load_lds(
        (const __attribute__((address_space(1))) void*)g,
        (__attribute__((address_space(3))) void*)l, 16, 0, 0);
}

// ---------------------------------------------------------------- fp32 -> bf16
__global__ __launch_bounds__(256) void conv_bf_kernel(
    const float* __restrict__ src, ushort* __restrict__ dst, int n8)
{
    int i = blockIdx.x * 256 + threadIdx.x;
    if (i >= n8) return;
    const float4* s = (const float4*)src;
    float4 a = s[i * 2], b = s[i * 2 + 1];
    uint4 o;
    o.x = pack2(a.x, a.y); o.y = pack2(a.z, a.w);
    o.z = pack2(b.x, b.y); o.w = pack2(b.z, b.w);
    ((uint4*)dst)[i] = o;
}

// ---------------------------------------------------------------- transpose fp32[R][C] -> bf16[C][R]
static __device__ __forceinline__ void tile_transpose_body(
    const float* __restrict__ src, int srcldc, ushort* __restrict__ dst, int Rd,
    int r0, int c0)
{
    __shared__ float t[64][65];
    int tid = threadIdx.x;
    int lr = tid >> 4, lc4 = (tid & 15) * 4;
    #pragma unroll
    for (int i = 0; i < 4; ++i) {
        float4 v = *(const float4*)&src[(size_t)(r0 + lr + i * 16) * srcldc + c0 + lc4];
        t[lr + i * 16][lc4 + 0] = v.x;
        t[lr + i * 16][lc4 + 1] = v.y;
        t[lr + i * 16][lc4 + 2] = v.z;
        t[lr + i * 16][lc4 + 3] = v.w;
    }
    __syncthreads();
    int oc = tid >> 2, orr = (tid & 3) * 16;
    uint4 u0, u1;
    u0.x = pack2(t[orr + 0][oc],  t[orr + 1][oc]);
    u0.y = pack2(t[orr + 2][oc],  t[orr + 3][oc]);
    u0.z = pack2(t[orr + 4][oc],  t[orr + 5][oc]);
    u0.w = pack2(t[orr + 6][oc],  t[orr + 7][oc]);
    u1.x = pack2(t[orr + 8][oc],  t[orr + 9][oc]);
    u1.y = pack2(t[orr + 10][oc], t[orr + 11][oc]);
    u1.z = pack2(t[orr + 12][oc], t[orr + 13][oc]);
    u1.w = pack2(t[orr + 14][oc], t[orr + 15][oc]);
    ushort* d = dst + (size_t)(c0 + oc) * Rd + r0 + orr;
    *(uint4*)&d[0] = u0;
    *(uint4*)&d[8] = u1;
}

__global__ __launch_bounds__(256) void transpose_bf_kernel(
    const float* __restrict__ src, ushort* __restrict__ dst, int R, int C)
{
    tile_transpose_body(src, C, dst, R, blockIdx.y * 64, blockIdx.x * 64);
}

// Wq/Wk/Wv [H, D, dh] -> WpT bf16 [1536][512]; row = p*512 + h*64 + e, col = d.
__global__ __launch_bounds__(256) void qkv_pack_kernel(
    const float* __restrict__ Wq, const float* __restrict__ Wk,
    const float* __restrict__ Wv, ushort* __restrict__ WpT)
{
    int z = blockIdx.z;
    int p = z >> 3, h = z & 7;
    const float* src = ((p == 0) ? Wq : (p == 1) ? Wk : Wv) + (size_t)h * D_MODEL * D_HEAD;
    ushort* dst = WpT + (size_t)(p * D_MODEL + h * D_HEAD) * D_MODEL;
    tile_transpose_body(src, D_HEAD, dst, D_MODEL, blockIdx.y * 64, 0);
}

__global__ __launch_bounds__(256) void pack_bias_kernel(
    const float* __restrict__ bq, const float* __restrict__ bk,
    const float* __restrict__ bv, float* __restrict__ bp)
{
    int idx = blockIdx.x * 256 + threadIdx.x;
    if (idx >= 3 * D_MODEL) return;
    int p = idx / D_MODEL;
    int h = (idx % D_MODEL) / D_HEAD;
    int e = idx % D_HEAD;
    const float* bb = (p == 0) ? bq : (p == 1) ? bk : bv;
    bp[idx] = bb[h * D_HEAD + e];
}

// ---------------------------------------------------------------- bf16 MFMA GEMM
// C = A[M,K] @ BT[N,K]^T (+bias) (+relu). BM=256, BN=128, BK=64.
// 512 threads = 8 waves (4 wr x 2 wc), wave tile 64x64 via 2x2 mfma_32x32x16.
// LDS: 2 bufs x (A 32KB + B 16KB) = 96KB dynamic. Issue stage(t+1) before
// compute(t); counted vmcnt(6); raw s_barrier once per K-step. T2 swizzle.
// OMODE: 0 = f32 out, 1 = bf16 out, 2 = QKV split (Qg/Kg natural, Vt transp).
template<int OMODE, bool RELU>
__global__ __launch_bounds__(512, 1) void gemm_bf16_kernel(
    const ushort* __restrict__ A, const ushort* __restrict__ BT,
    const float* __restrict__ bias, void* __restrict__ Cout,
    ushort* __restrict__ Qg, ushort* __restrict__ Kg, ushort* __restrict__ Vt,
    int M, int N, int K, int nbx)
{
    extern __shared__ __align__(16) char smem[];   // 2 x 49152

    const int tid = threadIdx.x;
    const int wid = tid >> 6, l = tid & 63;
    const int wr = wid >> 1, wc = wid & 1;

    // T1: bijective XCD swizzle (gridDim.x % 8 == 0 for all our launches)
    const int total = gridDim.x;
    const int cpx = total >> 3;
    const int flat = blockIdx.x;
    const int swz = (flat & 7) * cpx + (flat >> 3);
    const int bx = swz % nbx, by = swz / nbx;
    const int m0 = by * 256, n0 = bx * 128;

    // staging geometry: per-thread 6 x async16 (A:4, B:2), linear LDS dest,
    // pre-swizzled global source (involution within each row's 128B window).
    const int srow = tid >> 3;                         // 0..63 per issue
    const int sbyte = (tid & 7) * 16;
    const int ssw = sbyte ^ ((srow & 7) << 4);

    #define STAGE(t)                                                          \
    {                                                                         \
        const int kk_ = (t) * 64;                                             \
        char* dst_ = smem + ((t) & 1) * 49152;                                \
        _Pragma("unroll")                                                     \
        for (int i = 0; i < 4; ++i)                                           \
            async16((const char*)(A + (size_t)(m0 + i * 64 + srow) * K + kk_) \
                        + ssw,                                                \
                    dst_ + i * 8192 + tid * 16);                              \
        _Pragma("unroll")                                                     \
        for (int i = 0; i < 2; ++i)                                           \
            async16((const char*)(BT + (size_t)(n0 + i * 64 + srow) * K + kk_)\
                        + ssw,                                                \
                    dst_ + 32768 + i * 8192 + tid * 16);                      \
    }

    // fragment read geometry (32x32x16: lane row/col = l&31, k-half = l>>5)
    const int fl = l & 31, fh = l >> 5;
    const int frsw = (fl & 7) << 4;

    f32x16 acc[2][2] = {};

    STAGE(0);
    const int T = K >> 6;
    for (int t = 0; t < T; ++t) {
        __builtin_amdgcn_s_barrier();      // all waves done with buf[(t+1)&1]
        if (t + 1 < T) {
            STAGE(t + 1);
            asm volatile("s_waitcnt vmcnt(6)" ::: "memory");   // t landed
        } else {
            asm volatile("s_waitcnt vmcnt(0)" ::: "memory");
        }
        __builtin_amdgcn_sched_barrier(0);

        const char* bufA = smem + (t & 1) * 49152;
        const char* bufB = bufA + 32768;
        #pragma unroll
        for (int ks = 0; ks < 4; ++ks) {
            const int kb = ((ks * 32 + fh * 16) ^ frsw);
            bf16x8 af[2], bfv[2];
            #pragma unroll
            for (int mi = 0; mi < 2; ++mi)
                af[mi] = *(const bf16x8*)(bufA +
                    (wr * 64 + mi * 32 + fl) * 128 + kb);
            #pragma unroll
            for (int ni = 0; ni < 2; ++ni)
                bfv[ni] = *(const bf16x8*)(bufB +
                    (wc * 64 + ni * 32 + fl) * 128 + kb);
            #pragma unroll
            for (int mi = 0; mi < 2; ++mi)
                #pragma unroll
                for (int ni = 0; ni < 2; ++ni)
                    acc[mi][ni] = __builtin_amdgcn_mfma_f32_32x32x16_bf16(
                        af[mi], bfv[ni], acc[mi][ni], 0, 0, 0);
        }
    }

    // epilogue: 32x32 C/D layout col = l&31, row = (reg&3) + 8*(reg>>2) + 4*(l>>5)
    #pragma unroll
    for (int ni = 0; ni < 2; ++ni) {
        const int c = n0 + wc * 64 + ni * 32 + fl;
        const float bvv = bias ? bias[c] : 0.f;
        #pragma unroll
        for (int mi = 0; mi < 2; ++mi) {
            const int rbase = m0 + wr * 64 + mi * 32 + (fh << 2);
            float vv[16];
            #pragma unroll
            for (int reg = 0; reg < 16; ++reg) {
                float v = acc[mi][ni][reg] + bvv;
                if (RELU) v = fmaxf(v, 0.f);
                vv[reg] = v;
            }
            if (OMODE == 0) {
                #pragma unroll
                for (int reg = 0; reg < 16; ++reg) {
                    int r = rbase + (reg & 3) + ((reg >> 2) << 3);
                    ((float*)Cout)[(size_t)r * N + c] = vv[reg];
                }
            } else if (OMODE == 1) {
                #pragma unroll
                for (int reg = 0; reg < 16; ++reg) {
                    int r = rbase + (reg & 3) + ((reg >> 2) << 3);
                    ((ushort*)Cout)[(size_t)r * N + c] = f2bf(vv[reg]);
                }
            } else {
                const int p = n0 >> 9;            // tile fits in one 512-section
                const int h = (c >> 6) & 7, e = c & 63;
                #pragma unroll
                for (int q = 0; q < 4; ++q) {
                    int r0 = rbase + (q << 3);    // rows r0..r0+3 (same b)
                    int b = r0 >> 9, t0 = r0 & 511;
                    size_t bh = (size_t)(b * 8 + h);
                    if (p == 2) {
                        uint2 pk;
                        pk.x = pack2(vv[q * 4 + 0], vv[q * 4 + 1]);
                        pk.y = pack2(vv[q * 4 + 2], vv[q * 4 + 3]);
                        *(uint2*)&Vt[bh * 32768 + (size_t)e * 512 + t0] = pk;
                    } else {
                        ushort* dst = (p == 0 ? Qg : Kg) + bh * 32768 +
                                      (size_t)t0 * 64 + e;
                        dst[0]   = f2bf(vv[q * 4 + 0]);
                        dst[64]  = f2bf(vv[q * 4 + 1]);
                        dst[128] = f2bf(vv[q * 4 + 2]);
                        dst[192] = f2bf(vv[q * 4 + 3]);
                    }
                }
            }
        }
    }
    #undef STAGE
}

// ---------------------------------------------------------------- MFMA attention
// (unchanged from round 3 — passing, ~tens of µs)
__global__ __launch_bounds__(256) void attn_kernel(
    const ushort* __restrict__ Qg,   // [bh][t][e]
    const ushort* __restrict__ Kg,   // [bh][t][e]
    const ushort* __restrict__ Vt,   // [bh][e][t]
    ushort* __restrict__ O)          // [b*512+t][h*64+e]
{
    __shared__ __align__(16) char QP[8192];       // Q tile, then P strips
    __shared__ __align__(16) char KB[2][8192];
    __shared__ __align__(16) char VB[2][8192];

    const int bh = blockIdx.x, qb = blockIdx.y;
    const int tid = threadIdx.x;
    const int w = tid >> 6, l = tid & 63;

    const ushort* Qb = Qg + (size_t)bh * 32768;
    const ushort* Kb = Kg + (size_t)bh * 32768;
    const ushort* Vb = Vt + (size_t)bh * 32768;

    #pragma unroll
    for (int i = 0; i < 2; ++i) {
        int Xi = i * 4096 + tid * 16;
        int row = Xi >> 7;
        int sw = SWZ(Xi) & 127;
        async16((const char*)(Qb + (size_t)(qb * 64 + row) * 64) + sw, QP + Xi);
    }
    #define STAGEKV(kt, bb)                                                     \
        { _Pragma("unroll")                                                     \
          for (int i = 0; i < 2; ++i) {                                         \
              int Xi = i * 4096 + tid * 16;                                     \
              int row = Xi >> 7;                                                \
              int sw = SWZ(Xi) & 127;                                           \
              async16((const char*)(Kb + (size_t)((kt) * 64 + row) * 64) + sw,  \
                      KB[bb] + Xi);                                             \
              async16((const char*)(Vb + (size_t)row * 512 + (kt) * 64) + sw,   \
                      VB[bb] + Xi);                                             \
          } }
    STAGEKV(0, 0);
    __syncthreads();

    bf16x8 qf[2];
    {
        int qrow = w * 16 + (l & 15);
        #pragma unroll
        for (int ks = 0; ks < 2; ++ks) {
            int X = qrow * 128 + ks * 64 + (l >> 4) * 16;
            qf[ks] = *(const bf16x8*)(QP + SWZ(X));
        }
    }

    float mrow = -INFINITY, lrow = 0.f;
    f32x4 oacc[4] = {};

    for (int kt = 0; kt <= qb; ++kt) {
        int cur = kt & 1;
        if (kt < qb) STAGEKV(kt + 1, cur ^ 1);

        f32x4 sacc[4] = {};
        #pragma unroll
        for (int ks = 0; ks < 2; ++ks) {
            #pragma unroll
            for (int mi = 0; mi < 4; ++mi) {
                int X = (mi * 16 + (l & 15)) * 128 + ks * 64 + (l >> 4) * 16;
                bf16x8 kf = *(const bf16x8*)(KB[cur] + SWZ(X));
                sacc[mi] = __builtin_amdgcn_mfma_f32_16x16x32_bf16(
                    kf, qf[ks], sacc[mi], 0, 0, 0);
            }
        }

        float sv[16];
        float tmax = -INFINITY;
        const int qrow_t = w * 16 + (l & 15);
        #pragma unroll
        for (int mi = 0; mi < 4; ++mi)
            #pragma unroll
            for (int r = 0; r < 4; ++r) {
                float s = sacc[mi][r] * 0.125f;
                if (kt == qb) {
                    int key_l = mi * 16 + (l >> 4) * 4 + r;
                    if (key_l > qrow_t) s = -INFINITY;
                }
                sv[mi * 4 + r] = s;
                tmax = fmaxf(tmax, s);
            }
        tmax = fmaxf(tmax, __shfl_xor(tmax, 16));
        tmax = fmaxf(tmax, __shfl_xor(tmax, 32));
        float mnew = fmaxf(mrow, tmax);
        float corr = __expf(mrow - mnew);
        mrow = mnew;
        float psum = 0.f;
        #pragma unroll
        for (int i = 0; i < 16; ++i) { sv[i] = __expf(sv[i] - mnew); psum += sv[i]; }
        psum += __shfl_xor(psum, 16);
        psum += __shfl_xor(psum, 32);
        lrow = lrow * corr + psum;

        #pragma unroll
        for (int mi = 0; mi < 4; ++mi) {
            uint2 pk;
            pk.x = pack2(sv[mi * 4 + 0], sv[mi * 4 + 1]);
            pk.y = pack2(sv[mi * 4 + 2], sv[mi * 4 + 3]);
            int X = qrow_t * 128 + (mi * 16 + (l >> 4) * 4) * 2;
            *(uint2*)(QP + SWZ(X)) = pk;
        }

        #pragma unroll
        for (int r = 0; r < 4; ++r) {
            float cr = __shfl(corr, (l & 48) | ((l >> 4) * 4 + r));
            #pragma unroll
            for (int n = 0; n < 4; ++n) oacc[n][r] *= cr;
        }

        #pragma unroll
        for (int ks = 0; ks < 2; ++ks) {
            int Xa = qrow_t * 128 + ks * 64 + (l >> 4) * 16;
            bf16x8 pa = *(const bf16x8*)(QP + SWZ(Xa));
            #pragma unroll
            for (int n = 0; n < 4; ++n) {
                int Xb = (n * 16 + (l & 15)) * 128 + ks * 64 + (l >> 4) * 16;
                bf16x8 vb = *(const bf16x8*)(VB[cur] + SWZ(Xb));
                oacc[n] = __builtin_amdgcn_mfma_f32_16x16x32_bf16(
                    pa, vb, oacc[n], 0, 0, 0);
            }
        }
        __syncthreads();
    }

    float linv = 1.0f / lrow;
    const int b_ = bh >> 3, h_ = bh & 7;
    #pragma unroll
    for (int r = 0; r < 4; ++r) {
        float li = __shfl(linv, (l & 48) | ((l >> 4) * 4 + r));
        int trow = qb * 64 + w * 16 + (l >> 4) * 4 + r;
        size_t obase = ((size_t)b_ * 512 + trow) * 512 + h_ * 64 + (l & 15);
        #pragma unroll
        for (int n = 0; n < 4; ++n)
            O[obase + n * 16] = f2bf(oacc[n][r] * li);
    }
}

// ---------------------------------------------------------------- LN + residual
template<bool WBF>
__global__ __launch_bounds__(256) void ln_res_kernel(
    const float* __restrict__ v, const float* __restrict__ res,
    const float* __restrict__ g, const float* __restrict__ bb,
    float* __restrict__ out, ushort* __restrict__ out_bf)
{
    int row  = blockIdx.x * 4 + (threadIdx.x >> 6);
    int lane = threadIdx.x & 63;
    const float4* vp = (const float4*)(v + (size_t)row * D_MODEL);
    float4 a = vp[lane];
    float4 c = vp[lane + 64];
    float sum = a.x + a.y + a.z + a.w + c.x + c.y + c.z + c.w;
    float sq  = a.x*a.x + a.y*a.y + a.z*a.z + a.w*a.w
              + c.x*c.x + c.y*c.y + c.z*c.z + c.w*c.w;
    #pragma unroll
    for (int o = 1; o < 64; o <<= 1) {
        sum += __shfl_xor(sum, o);
        sq  += __shfl_xor(sq, o);
    }
    float mu   = sum * (1.f / 512.f);
    float var  = sq * (1.f / 512.f) - mu * mu;
    float rstd = rsqrtf(var + 1e-5f);

    const float4* rp = (const float4*)(res + (size_t)row * D_MODEL);
    const float4* gp = (const float4*)g;
    const float4* bp = (const float4*)bb;
    float4 r0 = rp[lane], r1 = rp[lane + 64];
    float4 g0 = gp[lane], g1 = gp[lane + 64];
    float4 b0 = bp[lane], b1 = bp[lane + 64];
    float4 o0, o1;
    o0.x = r0.x + (a.x - mu) * rstd * g0.x + b0.x;
    o0.y = r0.y + (a.y - mu) * rstd * g0.y + b0.y;
    o0.z = r0.z + (a.z - mu) * rstd * g0.z + b0.z;
    o0.w = r0.w + (a.w - mu) * rstd * g0.w + b0.w;
    o1.x = r1.x + (c.x - mu) * rstd * g1.x + b1.x;
    o1.y = r1.y + (c.y - mu) * rstd * g1.y + b1.y;
    o1.z = r1.z + (c.z - mu) * rstd * g1.z + b1.z;
    o1.w = r1.w + (c.w - mu) * rstd * g1.w + b1.w;
    float4* op = (float4*)(out + (size_t)row * D_MODEL);
    op[lane] = o0;
    op[lane + 64] = o1;
    if (WBF) {
        uint2 p0, p1;
        p0.x = pack2(o0.x, o0.y); p0.y = pack2(o0.z, o0.w);
        p1.x = pack2(o1.x, o1.y); p1.y = pack2(o1.z, o1.w);
        *(uint2*)&out_bf[(size_t)row * D_MODEL + lane * 4] = p0;
        *(uint2*)&out_bf[(size_t)row * D_MODEL + 256 + lane * 4] = p1;
    }
}

// ---------------------------------------------------------------- launch
extern "C" void kernel_launch(void* const* d_in, const int* in_sizes, int n_in,
                              void* d_out, int out_size, void* d_ws, size_t ws_size,
                              hipStream_t stream)
{
    const float* x     = (const float*)d_in[0];
    const float* Wq    = (const float*)d_in[1];
    const float* bq    = (const float*)d_in[2];
    const float* Wk    = (const float*)d_in[3];
    const float* bk    = (const float*)d_in[4];
    const float* Wv    = (const float*)d_in[5];
    const float* bv    = (const float*)d_in[6];
    const float* Wo    = (const float*)d_in[7];
    const float* bo    = (const float*)d_in[8];
    const float* ln1_g = (const float*)d_in[9];
    const float* ln1_b = (const float*)d_in[10];
    const float* W1    = (const float*)d_in[11];
    const float* b1    = (const float*)d_in[12];
    const float* W2    = (const float*)d_in[13];
    const float* b2    = (const float*)d_in[14];
    const float* ln2_g = (const float*)d_in[15];
    const float* ln2_b = (const float*)d_in[16];

    float* ws = (float*)d_ws;
    ushort* Qg      = (ushort*)(ws);               // 8,388,608 us
    ushort* Kg      = (ushort*)(ws + 4194304);     // 8,388,608 us
    ushort* Vt      = (ushort*)(ws + 8388608);     // 8,388,608 us
    ushort* O_bf    = (ushort*)(ws + 12582912);    // 8,388,608 us
    float*  attnb   = ws + 16777216;               // 8,388,608 f32 (ff2 aliases)
    float*  out1    = ws + 25165824;               // 8,388,608 f32
    ushort* out1_bf = (ushort*)(ws + 33554432);    // 8,388,608 us
    ushort* x_bf    = (ushort*)(ws + 37748736);    // 8,388,608 us
    ushort* WpT     = (ushort*)(ws + 41943040);    // 786,432 us
    ushort* WoT     = (ushort*)(ws + 42336256);    // 262,144 us
    ushort* W1T     = (ushort*)(ws + 42467328);    // 1,048,576 us
    ushort* W2T     = (ushort*)(ws + 42991616);    // 1,048,576 us
    float*  bp      = ws + 43515904;               // 1,536 f32
    ushort* ff1_bf  = (ushort*)ws;                 // 33,554,432 us (alias)
    float*  ff2     = attnb;

    // allow 96KB dynamic LDS (idempotent; ignore errors)
    (void)hipFuncSetAttribute(
        reinterpret_cast<const void*>(&gemm_bf16_kernel<2, false>),
        hipFuncAttributeMaxDynamicSharedMemorySize, 98304);
    (void)hipFuncSetAttribute(
        reinterpret_cast<const void*>(&gemm_bf16_kernel<0, false>),
        hipFuncAttributeMaxDynamicSharedMemorySize, 98304);
    (void)hipFuncSetAttribute(
        reinterpret_cast<const void*>(&gemm_bf16_kernel<1, true>),
        hipFuncAttributeMaxDynamicSharedMemorySize, 98304);

    conv_bf_kernel<<<dim3(4096), 256, 0, stream>>>(x, x_bf, NROWS * D_MODEL / 8);
    qkv_pack_kernel<<<dim3(1, 8, 24), 256, 0, stream>>>(Wq, Wk, Wv, WpT);
    transpose_bf_kernel<<<dim3(8, 8), 256, 0, stream>>>(Wo, WoT, 512, 512);
    transpose_bf_kernel<<<dim3(32, 8), 256, 0, stream>>>(W1, W1T, 512, 2048);
    transpose_bf_kernel<<<dim3(8, 32), 256, 0, stream>>>(W2, W2T, 2048, 512);
    pack_bias_kernel<<<dim3(6), 256, 0, stream>>>(bq, bk, bv, bp);

    // QKV: x @ Wp + bp -> Qg/Kg natural, Vt transposed. grid 12*64=768 (%8==0)
    gemm_bf16_kernel<2, false><<<dim3(768), 512, 98304, stream>>>(
        x_bf, WpT, bp, nullptr, Qg, Kg, Vt, NROWS, 1536, 512, 12);

    // attention -> O_bf
    attn_kernel<<<dim3(256, 8), 256, 0, stream>>>(Qg, Kg, Vt, O_bf);

    // attn = O @ Wo + bo  (fp32 out). grid 4*64=256
    gemm_bf16_kernel<0, false><<<dim3(256), 512, 98304, stream>>>(
        O_bf, WoT, bo, attnb, nullptr, nullptr, nullptr, NROWS, 512, 512, 4);

    // out1 = x + LN(attn); + bf16 copy
    ln_res_kernel<true><<<dim3(NROWS / 4), 256, 0, stream>>>(
        attnb, x, ln1_g, ln1_b, out1, out1_bf);

    // ff1 = relu(out1 @ W1 + b1) -> bf16. grid 16*64=1024
    gemm_bf16_kernel<1, true><<<dim3(1024), 512, 98304, stream>>>(
        out1_bf, W1T, b1, ff1_bf, nullptr, nullptr, nullptr, NROWS, 2048, 512, 16);

    // ff2 = ff1 @ W2 + b2  (fp32 out). grid 4*64=256, T=32
    gemm_bf16_kernel<0, false><<<dim3(256), 512, 98304, stream>>>(
        ff1_bf, W2T, b2, ff2, nullptr, nullptr, nullptr, NROWS, 512, 2048, 4);

    // out = out1 + LN(ff2)
    ln_res_kernel<false><<<dim3(NROWS / 4), 256, 0, stream>>>(
        ff2, out1, ln2_g, ln2_b, (float*)d_out, nullptr);
}